// Round 1
// baseline (899.040 us; speedup 1.0000x reference)
//
#include <hip/hip_runtime.h>
#include <hip/hip_bf16.h>

// RGCN forward, MI355X. N=100000 nodes, E=400000 edges, IN=OUT=256, R=200, B=32.
// Pipeline: pack W_r (coef@basis) -> bf16 MFMA-layout; counting-sort edges by
// etype; per-relation tile GEMM (64 edges x 256) with fused mean-scatter
// (unsafeAtomicAdd into d_out); self-loop GEMM writes d_out first.

#define NN 100000
#define EE 400000
#define RR 200
#define BB 32
#define MAXTILES 6456   // >= E/64 + R

typedef __attribute__((ext_vector_type(8))) short short8v;   // 8 x bf16 (16B)
typedef __attribute__((ext_vector_type(4))) float f32x4;

__device__ __forceinline__ unsigned short f2bf(float f) {
  unsigned u = __float_as_uint(f);
  u += 0x7FFF + ((u >> 16) & 1);          // RNE
  return (unsigned short)(u >> 16);
}

// ---------------------------------------------------------------------------
// Kernel 0: W_pk[r] = bf16(coef[r] @ basis), packed for MFMA B-fragments.
// Packed layout per relation: [ct=16][kt=8][lane=64][j=8] bf16, where
//   value = W_r[k = kt*32 + (lane>>4)*8 + j][n = ct*16 + (lane&15)].
// Each thread computes one 16B packed chunk for 8 consecutive relations.
__global__ __launch_bounds__(256) void k_wgen(const float* __restrict__ basis,
                                              const float* __restrict__ coef,
                                              short* __restrict__ wpk) {
  int t = blockIdx.x * 256 + threadIdx.x;   // 25 * 8192 = 204800 threads
  int rg  = t >> 13;                         // relation group 0..24 (8 rels each)
  int pk8 = t & 8191;                        // ct*512 + kt*64 + lane
  int lane = pk8 & 63;
  int kt = (pk8 >> 6) & 7;
  int ct = pk8 >> 9;
  int n  = ct * 16 + (lane & 15);
  int k0 = kt * 32 + ((lane >> 4) << 3);
  float acc[8][8];
#pragma unroll
  for (int r = 0; r < 8; ++r)
#pragma unroll
    for (int j = 0; j < 8; ++j) acc[r][j] = 0.f;
  for (int b = 0; b < BB; ++b) {
    float bas[8];
#pragma unroll
    for (int j = 0; j < 8; ++j) bas[j] = basis[b * 65536 + (k0 + j) * 256 + n];
#pragma unroll
    for (int r = 0; r < 8; ++r) {
      float c = coef[(rg * 8 + r) * BB + b];
#pragma unroll
      for (int j = 0; j < 8; ++j) acc[r][j] += c * bas[j];
    }
  }
#pragma unroll
  for (int r = 0; r < 8; ++r) {
    short8v v;
#pragma unroll
    for (int j = 0; j < 8; ++j) v[j] = (short)f2bf(acc[r][j]);
    *(short8v*)(wpk + (size_t)(rg * 8 + r) * 65536 + (size_t)pk8 * 8) = v;
  }
}

// Kernel 0b: pack self_loop_weight [256][256] f32 into same MFMA layout.
__global__ __launch_bounds__(256) void k_slwpk(const float* __restrict__ slw,
                                               short* __restrict__ spk) {
  int t = blockIdx.x * 256 + threadIdx.x;   // 8192 threads
  int lane = t & 63;
  int kt = (t >> 6) & 7;
  int ct = t >> 9;
  int n  = ct * 16 + (lane & 15);
  int k0 = kt * 32 + ((lane >> 4) << 3);
  short8v v;
#pragma unroll
  for (int j = 0; j < 8; ++j) v[j] = (short)f2bf(slw[(k0 + j) * 256 + n]);
  *(short8v*)(spk + (size_t)t * 8) = v;
}

// Kernel 1: histogram of etype + in-degree of dst.
__global__ __launch_bounds__(256) void k_hist(const int* __restrict__ etype,
                                              const int* __restrict__ dst,
                                              int* __restrict__ hist,
                                              int* __restrict__ deg) {
  int e = blockIdx.x * 256 + threadIdx.x;
  if (e < EE) {
    atomicAdd(&hist[etype[e]], 1);
    atomicAdd(&deg[dst[e]], 1);
  }
}

// Kernel 2 (single block): exclusive scans over 200 bins, emit tile descs,
// init scatter cursors. tdesc = {relation, rowstart, rows, 0}.
__global__ __launch_bounds__(256) void k_scan(const int* __restrict__ hist,
                                              int* __restrict__ cur,
                                              int4* __restrict__ tdesc) {
  __shared__ int h[RR];
  __shared__ int off[RR];
  __shared__ int toff[RR];
  __shared__ int tot;
  int tid = threadIdx.x;
  for (int i = tid; i < RR; i += 256) h[i] = hist[i];
  __syncthreads();
  if (tid == 0) {
    int s = 0, ts = 0;
    for (int r = 0; r < RR; ++r) {
      off[r] = s; s += h[r];
      toff[r] = ts; ts += (h[r] + 63) >> 6;
    }
    tot = ts;
  }
  __syncthreads();
  if (tid < RR) {
    int r = tid, cnt = h[r], base = off[r], to = toff[r];
    cur[r] = base;
    int nt = (cnt + 63) >> 6;
    for (int t2 = 0; t2 < nt; ++t2)
      tdesc[to + t2] = make_int4(r, base + t2 * 64, min(64, cnt - t2 * 64), 0);
  }
  for (int i = tot + tid; i < MAXTILES; i += 256)
    tdesc[i] = make_int4(0, 0, 0, 0);
}

// Kernel 3: scatter edge ids into relation-sorted perm.
__global__ __launch_bounds__(256) void k_scatter(const int* __restrict__ etype,
                                                 int* __restrict__ cur,
                                                 int* __restrict__ perm) {
  int e = blockIdx.x * 256 + threadIdx.x;
  if (e < EE) {
    int p = atomicAdd(&cur[etype[e]], 1);
    perm[p] = e;
  }
}

// ---------------------------------------------------------------------------
// Shared 64x256 @ 256x256 MFMA core. lA: LDS, 64 rows x 256 bf16, row-major
// with byte ^= ((row&7)<<4) swizzle. wpk: packed B (one relation).
__device__ __forceinline__ void gemm64(const char* lA, const short* __restrict__ wpk,
                                       f32x4 acc[4][4], int wave, int lane) {
  int l15 = lane & 15, lg = lane >> 4;
#pragma unroll
  for (int kt = 0; kt < 8; ++kt) {
    short8v a[4], b[4];
#pragma unroll
    for (int m = 0; m < 4; ++m) {
      int row = m * 16 + l15;
      int off = (row * 512 + kt * 64 + lg * 16) ^ ((row & 7) << 4);
      a[m] = *(const short8v*)(lA + off);
    }
#pragma unroll
    for (int c = 0; c < 4; ++c) {
      int ct = wave * 4 + c;
      b[c] = *(const short8v*)(wpk + (size_t)((ct * 8 + kt) * 64 + lane) * 8);
    }
#pragma unroll
    for (int m = 0; m < 4; ++m)
#pragma unroll
      for (int c = 0; c < 4; ++c)
        acc[m][c] = __builtin_amdgcn_mfma_f32_16x16x32_bf16(a[m], b[c], acc[m][c], 0, 0, 0);
  }
}

// Kernel 4: self-loop GEMM, overwrites d_out: out[n] = in_feat[n] @ slw.
__global__ __launch_bounds__(256) void k_self_gemm(const float* __restrict__ in_feat,
                                                   const short* __restrict__ spk,
                                                   float* __restrict__ out) {
  __shared__ short8v lAv[2048];              // 32 KiB
  char* lA = (char*)lAv;
  int n0 = blockIdx.x * 64;
  int tid = threadIdx.x;
  for (int it = tid; it < 4096; it += 256) {
    int row = it >> 6, q = it & 63;
    int n = n0 + row;
    float4 v = (n < NN) ? ((const float4*)(in_feat + (size_t)n * 256))[q]
                        : make_float4(0.f, 0.f, 0.f, 0.f);
    ushort4 hh;
    hh.x = f2bf(v.x); hh.y = f2bf(v.y); hh.z = f2bf(v.z); hh.w = f2bf(v.w);
    int off = (row * 512 + q * 8) ^ ((row & 7) << 4);
    *(ushort4*)(lA + off) = hh;
  }
  __syncthreads();
  f32x4 acc[4][4];
#pragma unroll
  for (int m = 0; m < 4; ++m)
#pragma unroll
    for (int c = 0; c < 4; ++c) acc[m][c] = (f32x4){0.f, 0.f, 0.f, 0.f};
  int wave = tid >> 6, lane = tid & 63;
  gemm64(lA, spk, acc, wave, lane);
  int l15 = lane & 15, lg = lane >> 4;
#pragma unroll
  for (int m = 0; m < 4; ++m)
#pragma unroll
    for (int j = 0; j < 4; ++j) {
      int n = n0 + m * 16 + lg * 4 + j;
      if (n < NN) {
        float* op = out + (size_t)n * 256 + wave * 64 + l15;
#pragma unroll
        for (int c = 0; c < 4; ++c) op[c * 16] = acc[m][c][j];
      }
    }
}

// Kernel 5: per-relation edge-message GEMM + fused mean scatter-add.
__global__ __launch_bounds__(256) void k_edge_gemm(const float* __restrict__ in_feat,
                                                   const short* __restrict__ wpk,
                                                   const int* __restrict__ src,
                                                   const int* __restrict__ dst,
                                                   const int* __restrict__ deg,
                                                   const int* __restrict__ perm,
                                                   const int4* __restrict__ tdesc,
                                                   float* __restrict__ out) {
  __shared__ short8v lAv[2048];              // 32 KiB
  __shared__ int lsrc[64];
  __shared__ int ldst[64];
  __shared__ float linv[64];
  char* lA = (char*)lAv;
  int4 d = tdesc[blockIdx.x];
  int rows = d.z;
  if (rows <= 0) return;
  int r = d.x, rs = d.y;
  int tid = threadIdx.x;
  if (tid < 64) {
    if (tid < rows) {
      int e = perm[rs + tid];
      lsrc[tid] = src[e];
      int dd = dst[e];
      ldst[tid] = dd;
      linv[tid] = 1.0f / (float)max(deg[dd], 1);
    } else {
      lsrc[tid] = -1; ldst[tid] = -1; linv[tid] = 0.f;
    }
  }
  __syncthreads();
  for (int it = tid; it < 4096; it += 256) {
    int row = it >> 6, q = it & 63;
    int s = lsrc[row];
    float4 v = (s >= 0) ? ((const float4*)(in_feat + (size_t)s * 256))[q]
                        : make_float4(0.f, 0.f, 0.f, 0.f);
    ushort4 hh;
    hh.x = f2bf(v.x); hh.y = f2bf(v.y); hh.z = f2bf(v.z); hh.w = f2bf(v.w);
    int off = (row * 512 + q * 8) ^ ((row & 7) << 4);
    *(ushort4*)(lA + off) = hh;
  }
  __syncthreads();
  f32x4 acc[4][4];
#pragma unroll
  for (int m = 0; m < 4; ++m)
#pragma unroll
    for (int c = 0; c < 4; ++c) acc[m][c] = (f32x4){0.f, 0.f, 0.f, 0.f};
  int wave = tid >> 6, lane = tid & 63;
  gemm64(lA, wpk + (size_t)r * 65536, acc, wave, lane);
  int l15 = lane & 15, lg = lane >> 4;
#pragma unroll
  for (int m = 0; m < 4; ++m)
#pragma unroll
    for (int j = 0; j < 4; ++j) {
      int row = m * 16 + lg * 4 + j;
      int dd = ldst[row];
      if (dd >= 0) {
        float inv = linv[row];
        float* op = out + (size_t)dd * 256 + wave * 64 + l15;
#pragma unroll
        for (int c = 0; c < 4; ++c) unsafeAtomicAdd(op + c * 16, acc[m][c][j] * inv);
      }
    }
}

// ---------------------------------------------------------------------------
extern "C" void kernel_launch(void* const* d_in, const int* in_sizes, int n_in,
                              void* d_out, int out_size, void* d_ws, size_t ws_size,
                              hipStream_t stream) {
  const float* in_feat = (const float*)d_in[0];
  const float* basis   = (const float*)d_in[1];
  const float* coef    = (const float*)d_in[2];
  const float* slw     = (const float*)d_in[3];
  const int*   src     = (const int*)d_in[4];
  const int*   dst     = (const int*)d_in[5];
  const int*   etype   = (const int*)d_in[6];
  float* out = (float*)d_out;

  char* w = (char*)d_ws;
  auto alloc = [&](size_t bytes) {
    char* p = w;
    w += (bytes + 255) & ~(size_t)255;
    return p;
  };
  short* wpk  = (short*)alloc((size_t)RR * 65536 * 2);   // 26.2 MB
  short* spk  = (short*)alloc(65536 * 2);
  int*   perm = (int*)alloc((size_t)EE * 4);
  int*   deg  = (int*)alloc((size_t)NN * 4);
  int*   hist = (int*)alloc(RR * 4);
  int*   cur  = (int*)alloc(RR * 4);
  int4*  tdesc = (int4*)alloc((size_t)MAXTILES * 16);

  hipMemsetAsync(hist, 0, RR * 4, stream);
  hipMemsetAsync(deg, 0, (size_t)NN * 4, stream);

  k_wgen<<<800, 256, 0, stream>>>(basis, coef, wpk);
  k_slwpk<<<32, 256, 0, stream>>>(slw, spk);
  k_hist<<<(EE + 255) / 256, 256, 0, stream>>>(etype, dst, hist, deg);
  k_scan<<<1, 256, 0, stream>>>(hist, cur, tdesc);
  k_scatter<<<(EE + 255) / 256, 256, 0, stream>>>(etype, cur, perm);
  k_self_gemm<<<(NN + 63) / 64, 256, 0, stream>>>(in_feat, spk, out);
  k_edge_gemm<<<MAXTILES, 256, 0, stream>>>(in_feat, wpk, src, dst, deg, perm, tdesc, out);
}

// Round 2
// 455.193 us; speedup vs baseline: 1.9751x; 1.9751x over previous
//
#include <hip/hip_runtime.h>
#include <hip/hip_bf16.h>

// RGCN forward, MI355X. N=100000 nodes, E=400000 edges, IN=OUT=256, R=200, B=32.
// Pipeline: pack W_r (coef@basis) -> bf16 MFMA-layout; counting-sort edges by
// etype (block-aggregated atomics); per-relation tile GEMM (64 edges x 256)
// with XCD-swizzled tiles + fused mean-scatter (unsafeAtomicAdd into d_out);
// self-loop GEMM writes d_out first.

#define NN 100000
#define EE 400000
#define RR 200
#define BB 32
#define MAXTILES 6456   // >= E/64 + R ; divisible by 8 for XCD swizzle
#define SCHUNK 2048

typedef __attribute__((ext_vector_type(8))) short short8v;   // 8 x bf16 (16B)
typedef __attribute__((ext_vector_type(4))) float f32x4;

__device__ __forceinline__ unsigned short f2bf(float f) {
  unsigned u = __float_as_uint(f);
  u += 0x7FFF + ((u >> 16) & 1);          // RNE
  return (unsigned short)(u >> 16);
}

// ---------------------------------------------------------------------------
// Kernel 0: W_pk[r] = bf16(coef[r] @ basis), packed for MFMA B-fragments.
// Packed layout per relation: [ct=16][kt=8][lane=64][j=8] bf16, where
//   value = W_r[k = kt*32 + (lane>>4)*8 + j][n = ct*16 + (lane&15)].
__global__ __launch_bounds__(256) void k_wgen(const float* __restrict__ basis,
                                              const float* __restrict__ coef,
                                              short* __restrict__ wpk) {
  int t = blockIdx.x * 256 + threadIdx.x;   // 25 * 8192 = 204800 threads
  int rg  = t >> 13;                         // relation group 0..24 (8 rels each)
  int pk8 = t & 8191;                        // ct*512 + kt*64 + lane
  int lane = pk8 & 63;
  int kt = (pk8 >> 6) & 7;
  int ct = pk8 >> 9;
  int n  = ct * 16 + (lane & 15);
  int k0 = kt * 32 + ((lane >> 4) << 3);
  float acc[8][8];
#pragma unroll
  for (int r = 0; r < 8; ++r)
#pragma unroll
    for (int j = 0; j < 8; ++j) acc[r][j] = 0.f;
  for (int b = 0; b < BB; ++b) {
    float bas[8];
#pragma unroll
    for (int j = 0; j < 8; ++j) bas[j] = basis[b * 65536 + (k0 + j) * 256 + n];
#pragma unroll
    for (int r = 0; r < 8; ++r) {
      float c = coef[(rg * 8 + r) * BB + b];
#pragma unroll
      for (int j = 0; j < 8; ++j) acc[r][j] += c * bas[j];
    }
  }
#pragma unroll
  for (int r = 0; r < 8; ++r) {
    short8v v;
#pragma unroll
    for (int j = 0; j < 8; ++j) v[j] = (short)f2bf(acc[r][j]);
    *(short8v*)(wpk + (size_t)(rg * 8 + r) * 65536 + (size_t)pk8 * 8) = v;
  }
}

// Kernel 0b: pack self_loop_weight [256][256] f32 into same MFMA layout.
__global__ __launch_bounds__(256) void k_slwpk(const float* __restrict__ slw,
                                               short* __restrict__ spk) {
  int t = blockIdx.x * 256 + threadIdx.x;   // 8192 threads
  int lane = t & 63;
  int kt = (t >> 6) & 7;
  int ct = t >> 9;
  int n  = ct * 16 + (lane & 15);
  int k0 = kt * 32 + ((lane >> 4) << 3);
  short8v v;
#pragma unroll
  for (int j = 0; j < 8; ++j) v[j] = (short)f2bf(slw[(k0 + j) * 256 + n]);
  *(short8v*)(spk + (size_t)t * 8) = v;
}

// Kernel 1: histogram of etype (LDS-aggregated) + in-degree of dst (direct:
// 100k addresses, avg contention 4). Grid-stride, 256 blocks.
__global__ __launch_bounds__(256) void k_hist(const int* __restrict__ etype,
                                              const int* __restrict__ dst,
                                              int* __restrict__ hist,
                                              int* __restrict__ deg) {
  __shared__ int lh[RR];
  int tid = threadIdx.x;
  for (int i = tid; i < RR; i += 256) lh[i] = 0;
  __syncthreads();
  for (int e = blockIdx.x * 256 + tid; e < EE; e += gridDim.x * 256) {
    atomicAdd(&lh[etype[e]], 1);
    atomicAdd(&deg[dst[e]], 1);
  }
  __syncthreads();
  for (int i = tid; i < RR; i += 256)
    if (lh[i]) atomicAdd(&hist[i], lh[i]);
}

// Kernel 2 (single block): exclusive scans over 200 bins, emit tile descs,
// init scatter cursors. tdesc = {relation, rowstart, rows, 0}.
__global__ __launch_bounds__(256) void k_scan(const int* __restrict__ hist,
                                              int* __restrict__ cur,
                                              int4* __restrict__ tdesc) {
  __shared__ int h[RR];
  __shared__ int off[RR];
  __shared__ int toff[RR];
  __shared__ int tot;
  int tid = threadIdx.x;
  for (int i = tid; i < RR; i += 256) h[i] = hist[i];
  __syncthreads();
  if (tid == 0) {
    int s = 0, ts = 0;
    for (int r = 0; r < RR; ++r) {
      off[r] = s; s += h[r];
      toff[r] = ts; ts += (h[r] + 63) >> 6;
    }
    tot = ts;
  }
  __syncthreads();
  if (tid < RR) {
    int r = tid, cnt = h[r], base = off[r], to = toff[r];
    cur[r] = base;
    int nt = (cnt + 63) >> 6;
    for (int t2 = 0; t2 < nt; ++t2)
      tdesc[to + t2] = make_int4(r, base + t2 * 64, min(64, cnt - t2 * 64), 0);
  }
  for (int i = tot + tid; i < MAXTILES; i += 256)
    tdesc[i] = make_int4(0, 0, 0, 0);
}

// Kernel 3: scatter edge ids into relation-sorted perm, block-aggregated:
// LDS hist -> one global reservation per (block,bin) -> LDS cursors.
__global__ __launch_bounds__(256) void k_scatter(const int* __restrict__ etype,
                                                 int* __restrict__ cur,
                                                 int* __restrict__ perm) {
  __shared__ int lh[RR];
  __shared__ int lbase[RR];
  __shared__ int lcur[RR];
  int tid = threadIdx.x;
  int e0 = blockIdx.x * SCHUNK;
  for (int i = tid; i < RR; i += 256) lh[i] = 0;
  __syncthreads();
  for (int i = tid; i < SCHUNK; i += 256) {
    int e = e0 + i;
    if (e < EE) atomicAdd(&lh[etype[e]], 1);
  }
  __syncthreads();
  for (int i = tid; i < RR; i += 256) {
    int c = lh[i];
    lbase[i] = c ? atomicAdd(&cur[i], c) : 0;
    lcur[i] = 0;
  }
  __syncthreads();
  for (int i = tid; i < SCHUNK; i += 256) {
    int e = e0 + i;
    if (e < EE) {
      int et = etype[e];
      int s = lbase[et] + atomicAdd(&lcur[et], 1);
      perm[s] = e;
    }
  }
}

// ---------------------------------------------------------------------------
// Shared 64x256 @ 256x256 MFMA core. lA: LDS, 64 rows x 256 bf16, row-major
// with byte ^= ((row&7)<<4) swizzle. wpk: packed B (one relation).
// B fragments software-prefetched one kt ahead.
__device__ __forceinline__ void gemm64(const char* lA, const short* __restrict__ wpk,
                                       f32x4 acc[4][4], int wave, int lane) {
  int l15 = lane & 15, lg = lane >> 4;
  const short* bp = wpk + (size_t)wave * 4 * 4096 + (size_t)lane * 8;
  short8v b[4];
#pragma unroll
  for (int c = 0; c < 4; ++c) b[c] = *(const short8v*)(bp + c * 4096);
#pragma unroll
  for (int kt = 0; kt < 8; ++kt) {
    short8v bn[4];
    if (kt < 7) {
#pragma unroll
      for (int c = 0; c < 4; ++c) bn[c] = *(const short8v*)(bp + c * 4096 + (kt + 1) * 512);
    }
    short8v a[4];
#pragma unroll
    for (int m = 0; m < 4; ++m) {
      int row = m * 16 + l15;
      int off = (row * 512 + kt * 64 + lg * 16) ^ ((row & 7) << 4);
      a[m] = *(const short8v*)(lA + off);
    }
#pragma unroll
    for (int m = 0; m < 4; ++m)
#pragma unroll
      for (int c = 0; c < 4; ++c)
        acc[m][c] = __builtin_amdgcn_mfma_f32_16x16x32_bf16(a[m], b[c], acc[m][c], 0, 0, 0);
    if (kt < 7) {
#pragma unroll
      for (int c = 0; c < 4; ++c) b[c] = bn[c];
    }
  }
}

// Kernel 4: self-loop GEMM, overwrites d_out: out[n] = in_feat[n] @ slw.
__global__ __launch_bounds__(256) void k_self_gemm(const float* __restrict__ in_feat,
                                                   const short* __restrict__ spk,
                                                   float* __restrict__ out) {
  __shared__ short8v lAv[2048];              // 32 KiB
  char* lA = (char*)lAv;
  int n0 = blockIdx.x * 64;
  int tid = threadIdx.x;
#pragma unroll
  for (int half = 0; half < 2; ++half) {
    float4 v[8];
#pragma unroll
    for (int u = 0; u < 8; ++u) {
      int it = half * 2048 + u * 256 + tid;
      int row = it >> 6, q = it & 63;
      int n = n0 + row;
      v[u] = (n < NN) ? ((const float4*)(in_feat + (size_t)n * 256))[q]
                      : make_float4(0.f, 0.f, 0.f, 0.f);
    }
#pragma unroll
    for (int u = 0; u < 8; ++u) {
      int it = half * 2048 + u * 256 + tid;
      int row = it >> 6, q = it & 63;
      ushort4 hh;
      hh.x = f2bf(v[u].x); hh.y = f2bf(v[u].y); hh.z = f2bf(v[u].z); hh.w = f2bf(v[u].w);
      int off = (row * 512 + q * 8) ^ ((row & 7) << 4);
      *(ushort4*)(lA + off) = hh;
    }
  }
  __syncthreads();
  f32x4 acc[4][4];
#pragma unroll
  for (int m = 0; m < 4; ++m)
#pragma unroll
    for (int c = 0; c < 4; ++c) acc[m][c] = (f32x4){0.f, 0.f, 0.f, 0.f};
  int wave = tid >> 6, lane = tid & 63;
  gemm64(lA, spk, acc, wave, lane);
  int l15 = lane & 15, lg = lane >> 4;
#pragma unroll
  for (int m = 0; m < 4; ++m)
#pragma unroll
    for (int j = 0; j < 4; ++j) {
      int n = n0 + m * 16 + lg * 4 + j;
      if (n < NN) {
        float* op = out + (size_t)n * 256 + wave * 64 + l15;
#pragma unroll
        for (int c = 0; c < 4; ++c) op[c * 16] = acc[m][c][j];
      }
    }
}

// Kernel 5: per-relation edge-message GEMM + fused mean scatter-add.
// Tiles XCD-swizzled so each XCD's L2 holds a contiguous slice of wpk.
__global__ __launch_bounds__(256) void k_edge_gemm(const float* __restrict__ in_feat,
                                                   const short* __restrict__ wpk,
                                                   const int* __restrict__ src,
                                                   const int* __restrict__ dst,
                                                   const int* __restrict__ deg,
                                                   const int* __restrict__ perm,
                                                   const int4* __restrict__ tdesc,
                                                   float* __restrict__ out) {
  __shared__ short8v lAv[2048];              // 32 KiB
  __shared__ int lsrc[64];
  __shared__ int ldst[64];
  __shared__ float linv[64];
  char* lA = (char*)lAv;
  // XCD swizzle: consecutive blockIdx round-robin XCDs; give XCD k the
  // contiguous tile range [k*807, (k+1)*807) -> wpk slice ~3.2MB fits 4MB L2.
  int bid = blockIdx.x;
  int tile = (bid & 7) * (MAXTILES / 8) + (bid >> 3);
  int4 d = tdesc[tile];
  int rows = d.z;
  if (rows <= 0) return;
  int r = d.x, rs = d.y;
  int tid = threadIdx.x;
  if (tid < 64) {
    if (tid < rows) {
      int e = perm[rs + tid];
      lsrc[tid] = src[e];
      int dd = dst[e];
      ldst[tid] = dd;
      linv[tid] = 1.0f / (float)max(deg[dd], 1);
    } else {
      lsrc[tid] = -1; ldst[tid] = -1; linv[tid] = 0.f;
    }
  }
  __syncthreads();
#pragma unroll
  for (int half = 0; half < 2; ++half) {
    float4 v[8];
#pragma unroll
    for (int u = 0; u < 8; ++u) {
      int it = half * 2048 + u * 256 + tid;
      int row = it >> 6, q = it & 63;
      int s = lsrc[row];
      v[u] = (s >= 0) ? ((const float4*)(in_feat + (size_t)s * 256))[q]
                      : make_float4(0.f, 0.f, 0.f, 0.f);
    }
#pragma unroll
    for (int u = 0; u < 8; ++u) {
      int it = half * 2048 + u * 256 + tid;
      int row = it >> 6, q = it & 63;
      ushort4 hh;
      hh.x = f2bf(v[u].x); hh.y = f2bf(v[u].y); hh.z = f2bf(v[u].z); hh.w = f2bf(v[u].w);
      int off = (row * 512 + q * 8) ^ ((row & 7) << 4);
      *(ushort4*)(lA + off) = hh;
    }
  }
  __syncthreads();
  f32x4 acc[4][4];
#pragma unroll
  for (int m = 0; m < 4; ++m)
#pragma unroll
    for (int c = 0; c < 4; ++c) acc[m][c] = (f32x4){0.f, 0.f, 0.f, 0.f};
  int wave = tid >> 6, lane = tid & 63;
  gemm64(lA, wpk + (size_t)r * 65536, acc, wave, lane);
  int l15 = lane & 15, lg = lane >> 4;
#pragma unroll
  for (int m = 0; m < 4; ++m)
#pragma unroll
    for (int j = 0; j < 4; ++j) {
      int row = m * 16 + lg * 4 + j;
      int dd = ldst[row];
      if (dd >= 0) {
        float inv = linv[row];
        float* op = out + (size_t)dd * 256 + wave * 64 + l15;
#pragma unroll
        for (int c = 0; c < 4; ++c) unsafeAtomicAdd(op + c * 16, acc[m][c][j] * inv);
      }
    }
}

// ---------------------------------------------------------------------------
extern "C" void kernel_launch(void* const* d_in, const int* in_sizes, int n_in,
                              void* d_out, int out_size, void* d_ws, size_t ws_size,
                              hipStream_t stream) {
  const float* in_feat = (const float*)d_in[0];
  const float* basis   = (const float*)d_in[1];
  const float* coef    = (const float*)d_in[2];
  const float* slw     = (const float*)d_in[3];
  const int*   src     = (const int*)d_in[4];
  const int*   dst     = (const int*)d_in[5];
  const int*   etype   = (const int*)d_in[6];
  float* out = (float*)d_out;

  char* w = (char*)d_ws;
  auto alloc = [&](size_t bytes) {
    char* p = w;
    w += (bytes + 255) & ~(size_t)255;
    return p;
  };
  short* wpk  = (short*)alloc((size_t)RR * 65536 * 2);   // 26.2 MB
  short* spk  = (short*)alloc(65536 * 2);
  int*   perm = (int*)alloc((size_t)EE * 4);
  int*   deg  = (int*)alloc((size_t)NN * 4);
  int*   hist = (int*)alloc(RR * 4);
  int*   cur  = (int*)alloc(RR * 4);
  int4*  tdesc = (int4*)alloc((size_t)MAXTILES * 16);

  hipMemsetAsync(hist, 0, RR * 4, stream);
  hipMemsetAsync(deg, 0, (size_t)NN * 4, stream);

  k_wgen<<<800, 256, 0, stream>>>(basis, coef, wpk);
  k_slwpk<<<32, 256, 0, stream>>>(slw, spk);
  k_hist<<<256, 256, 0, stream>>>(etype, dst, hist, deg);
  k_scan<<<1, 256, 0, stream>>>(hist, cur, tdesc);
  k_scatter<<<(EE + SCHUNK - 1) / SCHUNK, 256, 0, stream>>>(etype, cur, perm);
  k_self_gemm<<<(NN + 63) / 64, 256, 0, stream>>>(in_feat, spk, out);
  k_edge_gemm<<<MAXTILES, 256, 0, stream>>>(in_feat, wpk, src, dst, deg, perm, tdesc, out);
}